// Round 1
// baseline (109.675 us; speedup 1.0000x reference)
//
#include <hip/hip_runtime.h>

// Problem constants (fixed by the reference)
#define B_ 512
#define T_ 256
#define C_ 384
#define H_ 64

typedef __bf16 bf16;
typedef bf16  bf16x8 __attribute__((ext_vector_type(8)));
typedef bf16  bf16x4 __attribute__((ext_vector_type(4)));
typedef float f32x4  __attribute__((ext_vector_type(4)));

// LDS pitches (elements). +8 bf16 padding breaks power-of-2 bank stride;
// every pitch*2 is a multiple of 16B so ds_read_b128 stays aligned.
#define XP  392   // x stage: C + 8
#define QKP 72    // q/k: H + 8
#define VTP 264   // vT: T + 8
#define PP  40    // P tile: 32 + 8

__global__ __launch_bounds__(256, 1)
void head_fused(const float* __restrict__ x,
                const float* __restrict__ Wq,
                const float* __restrict__ Wk,
                const float* __restrict__ Wv,
                float* __restrict__ out)
{
    // 50176 + 36864 + 36864 + 33792 + 5120 = 162816 B <= 160 KiB
    __shared__ bf16 x_s[64 * XP];
    __shared__ bf16 q_s[T_ * QKP];
    __shared__ bf16 k_s[T_ * QKP];
    __shared__ bf16 vT_s[H_ * VTP];
    __shared__ bf16 p_s[4 * 16 * PP];

    const int tid  = threadIdx.x;
    const int wave = tid >> 6;
    const int lane = tid & 63;
    const int lr   = lane & 15;   // MFMA frag fast index (row of A / col of B,D)
    const int lg   = lane >> 4;   // group 0..3

    const int b = blockIdx.x;
    const float* xb = x + (size_t)b * T_ * C_;
    const float* Wmat[3] = { Wq, Wk, Wv };

    // ---------------- Phase 1: q,k,v projections (bf16 MFMA) ----------------
    // Each wave owns output column block n = wave (16 cols) for all 3 matrices,
    // so W sub-tiles are fetched once per m-block (no per-wave redundancy).
    const int nw = wave;

    for (int mb = 0; mb < 4; ++mb) {
        __syncthreads();   // protect x_s from previous iteration's readers
        // stage 64 rows of x as bf16 into LDS (coalesced float4 loads)
        {
            const float4* xg = reinterpret_cast<const float4*>(xb + mb * 64 * C_);
            #pragma unroll
            for (int it = 0; it < 24; ++it) {
                int i4 = tid + it * 256;         // 6144 float4 total
                float4 v4 = xg[i4];
                int row = i4 / 96;               // 96 float4 per row
                int col = (i4 % 96) * 4;
                bf16x4 h;
                h[0] = (bf16)v4.x; h[1] = (bf16)v4.y;
                h[2] = (bf16)v4.z; h[3] = (bf16)v4.w;
                *reinterpret_cast<bf16x4*>(&x_s[row * XP + col]) = h;
            }
        }
        __syncthreads();

        f32x4 acc[3][4];
        #pragma unroll
        for (int a = 0; a < 3; ++a)
            #pragma unroll
            for (int m = 0; m < 4; ++m)
                acc[a][m] = (f32x4){0.f, 0.f, 0.f, 0.f};

        #pragma unroll
        for (int ks = 0; ks < 12; ++ks) {
            // A-fragments: x[row=lr][k=lg*8+j] from LDS (16B contiguous)
            bf16x8 afr[4];
            #pragma unroll
            for (int m = 0; m < 4; ++m)
                afr[m] = *reinterpret_cast<const bf16x8*>(
                    &x_s[(m * 16 + lr) * XP + ks * 32 + lg * 8]);
            #pragma unroll
            for (int mat = 0; mat < 3; ++mat) {
                // B-fragment: W[k=ks*32+lg*8+j][nw*16+lr] gathered from global (L2-hot)
                const float* wp = Wmat[mat] + (ks * 32 + lg * 8) * H_ + nw * 16 + lr;
                bf16x8 bfr;
                #pragma unroll
                for (int j = 0; j < 8; ++j)
                    bfr[j] = (bf16)wp[j * H_];
                #pragma unroll
                for (int m = 0; m < 4; ++m)
                    acc[mat][m] = __builtin_amdgcn_mfma_f32_16x16x32_bf16(
                        afr[m], bfr, acc[mat][m], 0, 0, 0);
            }
        }

        // D layout: row = lg*4 + r, col = lr  (m89-verified). v stored transposed.
        #pragma unroll
        for (int m = 0; m < 4; ++m) {
            #pragma unroll
            for (int r = 0; r < 4; ++r) {
                int row = mb * 64 + m * 16 + lg * 4 + r;
                int col = nw * 16 + lr;
                q_s[row * QKP + col]  = (bf16)acc[0][m][r];
                k_s[row * QKP + col]  = (bf16)acc[1][m][r];
                vT_s[col * VTP + row] = (bf16)acc[2][m][r];
            }
        }
    }
    __syncthreads();   // q_s/k_s/vT_s complete and visible to all waves

    // ---------------- Phase 2: causal attention ----------------
    const float scale = 0.051031036307982884f;   // 384^-0.5 (note: C, not H)
    bf16* pw = &p_s[wave * 16 * PP];              // per-wave P buffer

    #pragma unroll 1
    for (int i = 0; i < 4; ++i) {
        const int qt  = i * 4 + wave;   // interleaved for causal load balance
        const int nkt = qt + 1;         // valid key tiles

        bf16x8 qf0 = *reinterpret_cast<const bf16x8*>(&q_s[(qt*16 + lr) * QKP + lg*8]);
        bf16x8 qf1 = *reinterpret_cast<const bf16x8*>(&q_s[(qt*16 + lr) * QKP + 32 + lg*8]);

        // full 16x256 score strip in registers (static indices only)
        float s[16][4];
        #pragma unroll
        for (int kt = 0; kt < 16; ++kt) {
            if (kt < nkt) {   // wave-uniform guard
                bf16x8 kf0 = *reinterpret_cast<const bf16x8*>(&k_s[(kt*16 + lr) * QKP + lg*8]);
                bf16x8 kf1 = *reinterpret_cast<const bf16x8*>(&k_s[(kt*16 + lr) * QKP + 32 + lg*8]);
                f32x4 sc = (f32x4){0.f, 0.f, 0.f, 0.f};
                sc = __builtin_amdgcn_mfma_f32_16x16x32_bf16(qf0, kf0, sc, 0, 0, 0);
                sc = __builtin_amdgcn_mfma_f32_16x16x32_bf16(qf1, kf1, sc, 0, 0, 0);
                #pragma unroll
                for (int r = 0; r < 4; ++r) {
                    float v = sc[r] * scale;
                    // diag tile: score row = lg*4+r, col = lr; mask col > row
                    if (kt == qt && lr > lg*4 + r) v = -1e30f;
                    s[kt][r] = v;
                }
            } else {
                #pragma unroll
                for (int r = 0; r < 4; ++r) s[kt][r] = -1e30f;  // exp -> 0
            }
        }

        // softmax stats: row (lg*4+r) lives across the 16 lanes of this group
        float inv[4];
        #pragma unroll
        for (int r = 0; r < 4; ++r) {
            float m = s[0][r];
            #pragma unroll
            for (int kt = 1; kt < 16; ++kt) m = fmaxf(m, s[kt][r]);
            m = fmaxf(m, __shfl_xor(m, 1));
            m = fmaxf(m, __shfl_xor(m, 2));
            m = fmaxf(m, __shfl_xor(m, 4));
            m = fmaxf(m, __shfl_xor(m, 8));
            float t = 0.f;
            #pragma unroll
            for (int kt = 0; kt < 16; ++kt) {
                float e = __expf(s[kt][r] - m);
                s[kt][r] = e;
                t += e;
            }
            t += __shfl_xor(t, 1);
            t += __shfl_xor(t, 2);
            t += __shfl_xor(t, 4);
            t += __shfl_xor(t, 8);
            inv[r] = 1.0f / t;
        }

        // PV: P through per-wave LDS tile to get A-fragment layout
        f32x4 oacc[4];
        #pragma unroll
        for (int n = 0; n < 4; ++n) oacc[n] = (f32x4){0.f, 0.f, 0.f, 0.f};

        const int nkk = (nkt + 1) >> 1;
        #pragma unroll
        for (int kk = 0; kk < 8; ++kk) {
            if (kk < nkk) {   // wave-uniform
                #pragma unroll
                for (int r = 0; r < 4; ++r) {
                    pw[(lg*4 + r) * PP + lr]      = (bf16)(s[2*kk][r]     * inv[r]);
                    pw[(lg*4 + r) * PP + 16 + lr] = (bf16)(s[2*kk + 1][r] * inv[r]);
                }
                // cross-lane LDS RAW within the wave: drain ds_writes first
                asm volatile("s_waitcnt lgkmcnt(0)" ::: "memory");
                bf16x8 pf = *reinterpret_cast<const bf16x8*>(&pw[lr * PP + lg * 8]);
                #pragma unroll
                for (int n = 0; n < 4; ++n) {
                    bf16x8 vf = *reinterpret_cast<const bf16x8*>(
                        &vT_s[(n*16 + lr) * VTP + kk*32 + lg*8]);
                    oacc[n] = __builtin_amdgcn_mfma_f32_16x16x32_bf16(pf, vf, oacc[n], 0, 0, 0);
                }
            }
        }

        // write out[b][qt*16 + row][h] fp32
        float* op = out + ((size_t)b * T_ + qt * 16) * H_;
        #pragma unroll
        for (int n = 0; n < 4; ++n)
            #pragma unroll
            for (int r = 0; r < 4; ++r)
                op[(lg*4 + r) * H_ + n*16 + lr] = oacc[n][r];
    }
}

extern "C" void kernel_launch(void* const* d_in, const int* in_sizes, int n_in,
                              void* d_out, int out_size, void* d_ws, size_t ws_size,
                              hipStream_t stream)
{
    (void)in_sizes; (void)n_in; (void)d_ws; (void)ws_size; (void)out_size;
    const float* x  = (const float*)d_in[0];
    const float* Wq = (const float*)d_in[1];
    const float* Wk = (const float*)d_in[2];
    const float* Wv = (const float*)d_in[3];
    float* o = (float*)d_out;
    head_fused<<<dim3(B_), dim3(256), 0, stream>>>(x, Wq, Wk, Wv, o);
}